// Round 14
// baseline (908.664 us; speedup 1.0000x reference)
//
#include <hip/hip_runtime.h>
#include <math.h>

#define SELF_VAL (-5e4f)

__device__ __forceinline__ unsigned short f2bf(float x) {
    unsigned b = __float_as_uint(x);
    b += 0x7FFFu + ((b >> 16) & 1u);
    return (unsigned short)(b >> 16);
}
__device__ __forceinline__ float bf2f(unsigned short h) {
    return __uint_as_float(((unsigned)h) << 16);
}

// ---------------- K0: re-layout rotations -> rotT2[h][k][col]  (4 x 64 x 256) ----------------
__global__ __launch_bounds__(256) void k_rotT(const float* __restrict__ rot,
                                              float* __restrict__ rotT2)
{
    int idx = blockIdx.x * 256 + threadIdx.x;    // 0..65535
    int h = idx >> 14, k = (idx >> 8) & 63, col = idx & 255;
    rotT2[idx] = rot[k * 1024 + h * 256 + col];
}

// ---------------- K1: fused qk/v GEMM (f32, 128x128, 8x8/thread) ----------------
// A in LDS (T14 prefetch); B streamed per-kk from L2 (Wqk/Wv are 2MB, L2-resident).
// LDS demand drops 4->2 ds_reads per kk: no longer LDS-bound.
// + fused rnorm epilogue for qk blocks (n0 < 512).
__global__ __launch_bounds__(256) void k_gemm_qkv(
    const float* __restrict__ Q, const float* __restrict__ Wqk,
    const float* __restrict__ Wv, float* __restrict__ qk, float* __restrict__ vv,
    float* __restrict__ rnorm)
{
    __shared__ float As[16][132];   // transposed: As[k][m]
    const int bx = blockIdx.x;
    const int mt = bx >> 3, nt = bx & 7;
    const int m0 = mt * 128, n0 = nt * 128;
    const int tid = threadIdx.x;
    const int ty = tid >> 4, tx = tid & 15;
    const float* Bsrc = (n0 < 512) ? (Wqk + n0) : (Wv + (n0 - 512));
    const int ar0 = tid >> 2, acq = (tid & 3) * 4;
    const int ar1 = 64 + ar0;
    const float* Aptr0 = Q + (size_t)(m0 + ar0) * 512 + acq;
    const float* Aptr1 = Q + (size_t)(m0 + ar1) * 512 + acq;
    const float* Bp0 = Bsrc + tx * 4;
    const float* Bp1 = Bsrc + 64 + tx * 4;
    float acc[8][8] = {};
    float4 a0 = *(const float4*)(Aptr0);
    float4 a1 = *(const float4*)(Aptr1);
    for (int k0 = 0; k0 < 512; k0 += 16) {
        As[acq+0][ar0]=a0.x; As[acq+1][ar0]=a0.y; As[acq+2][ar0]=a0.z; As[acq+3][ar0]=a0.w;
        As[acq+0][ar1]=a1.x; As[acq+1][ar1]=a1.y; As[acq+2][ar1]=a1.z; As[acq+3][ar1]=a1.w;
        __syncthreads();
        if (k0 + 16 < 512) {
            a0 = *(const float4*)(Aptr0 + k0 + 16);
            a1 = *(const float4*)(Aptr1 + k0 + 16);
        }
        #pragma unroll 8
        for (int kk = 0; kk < 16; kk++) {
            float4 b4a = *(const float4*)(Bp0 + (size_t)(k0 + kk) * 512);
            float4 b4b = *(const float4*)(Bp1 + (size_t)(k0 + kk) * 512);
            float a_[8];
            *(float4*)&a_[0] = *(float4*)&As[kk][ty*4];
            *(float4*)&a_[4] = *(float4*)&As[kk][64 + ty*4];
            float b_[8] = {b4a.x, b4a.y, b4a.z, b4a.w, b4b.x, b4b.y, b4b.z, b4b.w};
            #pragma unroll
            for (int i = 0; i < 8; i++)
                #pragma unroll
                for (int j = 0; j < 8; j++)
                    acc[i][j] += a_[i] * b_[j];
        }
        __syncthreads();
    }
    #pragma unroll
    for (int ig = 0; ig < 2; ig++) {
        #pragma unroll
        for (int i = 0; i < 4; i++) {
            int row = m0 + ig*64 + ty*4 + i;
            int b = row >> 11, t = row & 2047;
            #pragma unroll
            for (int jg = 0; jg < 2; jg++) {
                int n = n0 + jg*64 + tx*4;
                float4 r4 = make_float4(acc[ig*4+i][jg*4+0], acc[ig*4+i][jg*4+1],
                                        acc[ig*4+i][jg*4+2], acc[ig*4+i][jg*4+3]);
                if (n < 512) {
                    *(float4*)(qk + ((size_t)((b*8 + (n>>6))*2048 + t))*64 + (n&63)) = r4;
                } else {
                    int nv = n - 512;
                    *(float4*)(vv + ((size_t)((b*8 + (nv>>6))*2048 + t))*64 + (nv&63)) = r4;
                }
            }
        }
    }
    // ---- fused rnorm: this block owns complete 64-dim vectors for 2 heads x 128 tokens ----
    if (n0 < 512) {
        #pragma unroll
        for (int jg = 0; jg < 2; jg++) {
            int h = (n0 + jg*64) >> 6;
            #pragma unroll
            for (int ig = 0; ig < 2; ig++) {
                #pragma unroll
                for (int i = 0; i < 4; i++) {
                    float s = acc[ig*4+i][jg*4+0]*acc[ig*4+i][jg*4+0]
                            + acc[ig*4+i][jg*4+1]*acc[ig*4+i][jg*4+1]
                            + acc[ig*4+i][jg*4+2]*acc[ig*4+i][jg*4+2]
                            + acc[ig*4+i][jg*4+3]*acc[ig*4+i][jg*4+3];
                    s += __shfl_xor(s, 1);
                    s += __shfl_xor(s, 2);
                    s += __shfl_xor(s, 4);
                    s += __shfl_xor(s, 8);
                    if (tx == 0) {
                        int row = m0 + ig*64 + ty*4 + i;
                        int b = row >> 11, t = row & 2047;
                        rnorm[((size_t)(b*8 + h))*2048 + t] = 1.0f / fmaxf(sqrtf(s), 1e-12f);
                    }
                }
            }
        }
    }
}

// ---------------- K2: hash = f32 GEMM (128 tokens, K=64) + signed argmax ----------------
// FROZEN round-6 body (287 us, VGPR 64, VALUBusy 70%).
__global__ __launch_bounds__(256) void k_hash(const float* __restrict__ qk,
    const float* __restrict__ rotT2, unsigned* __restrict__ buckets)
{
    __shared__ float As[64*128];    // As[k][row], pitch 128 (32 KB)
    const int bx = blockIdx.x;
    const int bm = bx >> 4;
    const int row0 = (bx & 15) << 7;             // token base within bm
    const int tid = threadIdx.x;
    const int ty = tid >> 4, tx = tid & 15;
    // ---- stage A (128 tokens x 64 k), transposed ----
    {
        const int r = tid >> 1;
        const int kb = (tid & 1) * 8;            // float4 units
        const float* src = qk + ((size_t)(bm*2048 + row0 + r))*64;
        #pragma unroll
        for (int c = 0; c < 8; c++) {
            float4 a4 = *(const float4*)(src + (size_t)(kb + c)*4);
            int k = (kb + c)*4;
            As[(k+0)*128 + r] = a4.x;
            As[(k+1)*128 + r] = a4.y;
            As[(k+2)*128 + r] = a4.z;
            As[(k+3)*128 + r] = a4.w;
        }
    }
    __syncthreads();
    #pragma unroll 1
    for (int h = 0; h < 4; h++) {
        float bv[8]; unsigned bi[8];
        #pragma unroll
        for (int i = 0; i < 8; i++) { bv[i] = -3.402823466e38f; bi[i] = 0u; }
        #pragma unroll 1
        for (int ch = 0; ch < 4; ch++) {
            const float* bsrc = rotT2 + (size_t)h*16384 + ch*64 + tx*4;
            float acc[8][4] = {};
            #pragma unroll 16
            for (int kk = 0; kk < 64; kk++) {
                float4 b4 = *(const float4*)(bsrc + (size_t)kk*256);
                float a_[8];
                *(float4*)&a_[0] = *(float4*)&As[kk*128 + ty*4];
                *(float4*)&a_[4] = *(float4*)&As[kk*128 + 64 + ty*4];
                float b_[4] = {b4.x, b4.y, b4.z, b4.w};
                #pragma unroll
                for (int i = 0; i < 8; i++)
                    #pragma unroll
                    for (int j = 0; j < 4; j++)
                        acc[i][j] += a_[i] * b_[j];
            }
            #pragma unroll
            for (int j = 0; j < 4; j++) {
                unsigned c0 = (unsigned)(ch*64 + tx*4 + j);
                unsigned nc0 = 256u + c0;
                #pragma unroll
                for (int i = 0; i < 8; i++) {
                    float v = acc[i][j];
                    if (v > bv[i] || (v == bv[i] && c0 < bi[i])) { bv[i] = v; bi[i] = c0; }
                    float nv = -v;
                    if (nv > bv[i] || (nv == bv[i] && nc0 < bi[i])) { bv[i] = nv; bi[i] = nc0; }
                }
            }
        }
        #pragma unroll
        for (int i = 0; i < 8; i++) {
            #pragma unroll
            for (int d = 1; d < 16; d <<= 1) {
                float ov = __shfl_xor(bv[i], d);
                unsigned oi = (unsigned)__shfl_xor((int)bi[i], d);
                if (ov > bv[i] || (ov == bv[i] && oi < bi[i])) { bv[i] = ov; bi[i] = oi; }
            }
        }
        if (tx == 0) {
            #pragma unroll
            for (int i = 0; i < 8; i++) {
                int r = (i < 4) ? (ty*4 + i) : (64 + ty*4 + (i - 4));
                buckets[((size_t)(bm*4 + h))*2048 + row0 + r] = bi[i];
            }
        }
    }
}

// ---------------- K3: stable counting sort per (bm,hash) ----------------
__global__ __launch_bounds__(256) void k_sort(const unsigned* __restrict__ buckets,
                                              unsigned* __restrict__ st)
{
    __shared__ unsigned whist[4][512];
    __shared__ unsigned baseb[512];
    const int seg = blockIdx.x;                  // bm*4+h
    const unsigned* bk = buckets + (size_t)seg * 2048;
    unsigned* out = st + (size_t)seg * 2048;
    const int tid = threadIdx.x, w = tid >> 6, lane = tid & 63;
    for (int b = tid; b < 2048; b += 256) ((unsigned*)whist)[b] = 0u;
    __syncthreads();
    unsigned myb[8];
    #pragma unroll
    for (int r = 0; r < 8; r++) {
        int pos = w*512 + r*64 + lane;
        myb[r] = bk[pos];
        atomicAdd(&whist[w][myb[r]], 1u);
    }
    __syncthreads();
    for (int b = tid; b < 512; b += 256) {
        unsigned p = 0;
        #pragma unroll
        for (int ww = 0; ww < 4; ww++) { unsigned t = whist[ww][b]; whist[ww][b] = p; p += t; }
        baseb[b] = p;
    }
    __syncthreads();
    if (tid == 0) {
        unsigned run = 0;
        for (int b = 0; b < 512; b++) { unsigned t = baseb[b]; baseb[b] = run; run += t; }
    }
    __syncthreads();
    for (int b = tid; b < 512; b += 256) {
        unsigned bb = baseb[b];
        #pragma unroll
        for (int ww = 0; ww < 4; ww++) whist[ww][b] += bb;
    }
    __syncthreads();
    for (int r = 0; r < 8; r++) {
        unsigned b = myb[r];
        int pos = w*512 + r*64 + lane;
        unsigned base = whist[w][b];             // read before this round's bumps
        unsigned rank = 0;
        for (int j = 0; j < 64; j++) {
            unsigned bj = __shfl(b, j);
            rank += (j < lane && bj == b) ? 1u : 0u;
        }
        out[base + rank] = (unsigned)pos;
        atomicAdd(&whist[w][b], 1u);
    }
}

// ---------------- K4: chunked LSH attention (bf16 oh output) ----------------
__global__ __launch_bounds__(256) void k_attn(const float* __restrict__ qk,
    const float* __restrict__ vv, const float* __restrict__ rnorm,
    const unsigned* __restrict__ st, unsigned short* __restrict__ oh16,
    float* __restrict__ logits)
{
    __shared__ float qs[68][68];
    __shared__ float vs[68][68];
    __shared__ unsigned P[68];
    __shared__ float rn[68];
    const int sid = blockIdx.x;
    const int stripi = sid & 31;
    const int seg = sid >> 5;
    const int bm = seg >> 2, h = seg & 3;
    const int G0 = (h*512 + stripi*16) * 4;      // first q slot (global, 0..8191)
    const int tid = threadIdx.x;
    for (int j = tid; j < 68; j += 256) {
        int G = (G0 - 4 + j) & 8191;
        int hg = G >> 11, sg = G & 2047;
        unsigned tok = st[((size_t)(bm*4 + hg))*2048 + sg];
        P[j] = tok;
        rn[j] = rnorm[bm*2048 + (int)tok];
    }
    __syncthreads();
    for (int e = tid; e < 68*16; e += 256) {
        int j = e >> 4, fq = e & 15;
        unsigned tok = P[j];
        size_t base = ((size_t)(bm*2048 + (int)tok))*64 + fq*4;
        *(float4*)&qs[j][fq*4] = *(const float4*)(qk + base);
        *(float4*)&vs[j][fq*4] = *(const float4*)(vv + base);
    }
    __syncthreads();
    const int w = tid >> 6, lane = tid & 63;
    const int half = lane >> 5, qi = (lane >> 3) & 3, jj = lane & 7;
    const int fb = lane & 7;
    for (int cp = 0; cp < 2; cp++) {
        int c = w*4 + cp*2 + half;               // local chunk 0..15
        int jq = 4 + c*4 + qi;
        int jk = c*4 + jj;
        float dot = 0.f;
        #pragma unroll
        for (int fq = 0; fq < 16; fq++) {
            float4 q4 = *(float4*)&qs[jq][fq*4];
            float4 k4 = *(float4*)&qs[jk][fq*4];
            dot += q4.x*k4.x + q4.y*k4.y + q4.z*k4.z + q4.w*k4.w;
        }
        dot *= 0.125f * rn[jk];
        if (P[jq] == P[jk]) dot = SELF_VAL;
        float m = dot;
        m = fmaxf(m, __shfl_xor(m, 1));
        m = fmaxf(m, __shfl_xor(m, 2));
        m = fmaxf(m, __shfl_xor(m, 4));
        float ex = expf(dot - m);
        float s = ex;
        s += __shfl_xor(s, 1); s += __shfl_xor(s, 2); s += __shfl_xor(s, 4);
        float lse = m + logf(s);
        float p = expf(dot - lse);
        unsigned tq = P[jq];
        if (jj == 0) logits[((size_t)(bm*4 + h))*2048 + tq] = lse;
        float a0=0,a1=0,a2=0,a3=0,a4a=0,a5=0,a6=0,a7=0;
        #pragma unroll
        for (int j2 = 0; j2 < 8; j2++) {
            float pj = __shfl(p, (lane & 0x38) | j2);
            float4 va = *(float4*)&vs[c*4 + j2][fb*8];
            float4 vb = *(float4*)&vs[c*4 + j2][fb*8 + 4];
            a0 += pj*va.x; a1 += pj*va.y; a2 += pj*va.z; a3 += pj*va.w;
            a4a += pj*vb.x; a5 += pj*vb.y; a6 += pj*vb.z; a7 += pj*vb.w;
        }
        union { unsigned short s[8]; uint4 v; } ob;
        ob.s[0]=f2bf(a0); ob.s[1]=f2bf(a1); ob.s[2]=f2bf(a2); ob.s[3]=f2bf(a3);
        ob.s[4]=f2bf(a4a); ob.s[5]=f2bf(a5); ob.s[6]=f2bf(a6); ob.s[7]=f2bf(a7);
        *(uint4*)(oh16 + ((size_t)((bm*4 + h)*2048 + (int)tq))*64 + fb*8) = ob.v;
    }
}

// ---------------- K5: combine hash rounds (bf16 oh input) ----------------
__global__ __launch_bounds__(256) void k_combine(const unsigned short* __restrict__ oh16,
    const float* __restrict__ logits, float* __restrict__ comb)
{
    int w = threadIdx.x >> 6, lane = threadIdx.x & 63;
    int row = blockIdx.x * 4 + w;                // bm*2048+t
    int bm = row >> 11, t = row & 2047;
    int b = bm >> 3, head = bm & 7;
    float l0 = logits[((size_t)(bm*4 + 0))*2048 + t];
    float l1 = logits[((size_t)(bm*4 + 1))*2048 + t];
    float l2 = logits[((size_t)(bm*4 + 2))*2048 + t];
    float l3 = logits[((size_t)(bm*4 + 3))*2048 + t];
    float m = fmaxf(fmaxf(l0, l1), fmaxf(l2, l3));
    float e0 = expf(l0 - m), e1 = expf(l1 - m), e2 = expf(l2 - m), e3 = expf(l3 - m);
    float inv = 1.0f / (e0 + e1 + e2 + e3);
    float o = 0.f;
    o += (e0*inv) * bf2f(oh16[((size_t)((bm*4+0)*2048 + t))*64 + lane]);
    o += (e1*inv) * bf2f(oh16[((size_t)((bm*4+1)*2048 + t))*64 + lane]);
    o += (e2*inv) * bf2f(oh16[((size_t)((bm*4+2)*2048 + t))*64 + lane]);
    o += (e3*inv) * bf2f(oh16[((size_t)((bm*4+3)*2048 + t))*64 + lane]);
    comb[((size_t)(b*2048 + t))*512 + head*64 + lane] = o;
}

// ---------------- K6: output GEMM + bias (f32, 128x128, 8x8/thread) ----------------
// A in LDS (T14 prefetch); B (Wout, 1MB) streamed per-kk from L2.
__global__ __launch_bounds__(256) void k_gemm_out(
    const float* __restrict__ A, const float* __restrict__ Wout,
    const float* __restrict__ bias, float* __restrict__ out)
{
    __shared__ float As[16][132];
    const int bx = blockIdx.x;
    const int mt = bx >> 2, nt = bx & 3;
    const int m0 = mt * 128, n0 = nt * 128;
    const int tid = threadIdx.x;
    const int ty = tid >> 4, tx = tid & 15;
    const int ar0 = tid >> 2, acq = (tid & 3) * 4;
    const int ar1 = 64 + ar0;
    const float* Aptr0 = A + (size_t)(m0 + ar0) * 512 + acq;
    const float* Aptr1 = A + (size_t)(m0 + ar1) * 512 + acq;
    const float* Bp0 = Wout + n0 + tx * 4;
    const float* Bp1 = Wout + n0 + 64 + tx * 4;
    float acc[8][8] = {};
    float4 a0 = *(const float4*)(Aptr0);
    float4 a1 = *(const float4*)(Aptr1);
    for (int k0 = 0; k0 < 512; k0 += 16) {
        As[acq+0][ar0]=a0.x; As[acq+1][ar0]=a0.y; As[acq+2][ar0]=a0.z; As[acq+3][ar0]=a0.w;
        As[acq+0][ar1]=a1.x; As[acq+1][ar1]=a1.y; As[acq+2][ar1]=a1.z; As[acq+3][ar1]=a1.w;
        __syncthreads();
        if (k0 + 16 < 512) {
            a0 = *(const float4*)(Aptr0 + k0 + 16);
            a1 = *(const float4*)(Aptr1 + k0 + 16);
        }
        #pragma unroll 8
        for (int kk = 0; kk < 16; kk++) {
            float4 b4a = *(const float4*)(Bp0 + (size_t)(k0 + kk) * 512);
            float4 b4b = *(const float4*)(Bp1 + (size_t)(k0 + kk) * 512);
            float a_[8];
            *(float4*)&a_[0] = *(float4*)&As[kk][ty*4];
            *(float4*)&a_[4] = *(float4*)&As[kk][64 + ty*4];
            float b_[8] = {b4a.x, b4a.y, b4a.z, b4a.w, b4b.x, b4b.y, b4b.z, b4b.w};
            #pragma unroll
            for (int i = 0; i < 8; i++)
                #pragma unroll
                for (int j = 0; j < 8; j++)
                    acc[i][j] += a_[i] * b_[j];
        }
        __syncthreads();
    }
    #pragma unroll
    for (int ig = 0; ig < 2; ig++) {
        #pragma unroll
        for (int i = 0; i < 4; i++) {
            int row = m0 + ig*64 + ty*4 + i;
            #pragma unroll
            for (int jg = 0; jg < 2; jg++) {
                int n = n0 + jg*64 + tx*4;
                float4 bb = *(const float4*)(bias + n);
                float4 r4 = make_float4(acc[ig*4+i][jg*4+0] + bb.x, acc[ig*4+i][jg*4+1] + bb.y,
                                        acc[ig*4+i][jg*4+2] + bb.z, acc[ig*4+i][jg*4+3] + bb.w);
                *(float4*)(out + (size_t)row * 512 + n) = r4;
            }
        }
    }
}

extern "C" void kernel_launch(void* const* d_in, const int* in_sizes, int n_in,
                              void* d_out, int out_size, void* d_ws, size_t ws_size,
                              hipStream_t stream)
{
    const float* Q    = (const float*)d_in[0];
    const float* Wqk  = (const float*)d_in[3];
    const float* Wv   = (const float*)d_in[4];
    const float* Wout = (const float*)d_in[5];
    const float* bout = (const float*)d_in[6];
    const float* rot  = (const float*)d_in[7];
    float* ws = (float*)d_ws;
    float* qk     = ws;                       // 8,388,608 floats
    float* vv     = ws + 8388608;             // 8,388,608
    unsigned short* oh16 = (unsigned short*)(ws + 16777216);  // 33.5M ushort
    float* comb   = ws + 50331648;            // 8,388,608
    float* rnorm  = ws + 58720256;            // 131,072
    float* logits = ws + 58851328;            // 524,288
    unsigned* buckets = (unsigned*)(ws + 59375616);   // 524,288
    unsigned* st      = (unsigned*)(ws + 59899904);   // 524,288
    float* rotT2  = ws + 60424192;            // 65,536
    float* out = (float*)d_out;

    k_rotT    <<<dim3(256),  dim3(256), 0, stream>>>(rot, rotT2);
    k_gemm_qkv<<<dim3(1024), dim3(256), 0, stream>>>(Q, Wqk, Wv, qk, vv, rnorm);
    k_hash    <<<dim3(1024), dim3(256), 0, stream>>>(qk, rotT2, buckets);
    k_sort    <<<dim3(256),  dim3(256), 0, stream>>>(buckets, st);
    k_attn    <<<dim3(8192), dim3(256), 0, stream>>>(qk, vv, rnorm, st, oh16, logits);
    k_combine <<<dim3(32768),dim3(256), 0, stream>>>(oh16, logits, comb);
    k_gemm_out<<<dim3(512),  dim3(256), 0, stream>>>(comb, Wout, bout, out);
}

// Round 15
// 708.253 us; speedup vs baseline: 1.2830x; 1.2830x over previous
//
#include <hip/hip_runtime.h>
#include <math.h>

#define SELF_VAL (-5e4f)

__device__ __forceinline__ unsigned short f2bf(float x) {
    unsigned b = __float_as_uint(x);
    b += 0x7FFFu + ((b >> 16) & 1u);
    return (unsigned short)(b >> 16);
}
__device__ __forceinline__ float bf2f(unsigned short h) {
    return __uint_as_float(((unsigned)h) << 16);
}

// ---------------- K0: re-layout rotations -> rotT2[h][k][col]  (4 x 64 x 256) ----------------
__global__ __launch_bounds__(256) void k_rotT(const float* __restrict__ rot,
                                              float* __restrict__ rotT2)
{
    int idx = blockIdx.x * 256 + threadIdx.x;    // 0..65535
    int h = idx >> 14, k = (idx >> 8) & 63, col = idx & 255;
    rotT2[idx] = rot[k * 1024 + h * 256 + col];
}

// ---------------- K1: fused qk/v GEMM (f32, 128x128, 8x8/thread, T14 dbuf) ----------------
// + fused rnorm epilogue for qk blocks (n0 < 512): deletes the k_rnorm pass.
__global__ __launch_bounds__(256) void k_gemm_qkv(
    const float* __restrict__ Q, const float* __restrict__ Wqk,
    const float* __restrict__ Wv, float* __restrict__ qk, float* __restrict__ vv,
    float* __restrict__ rnorm)
{
    __shared__ float As[16][132];   // transposed: As[k][m]
    __shared__ float Bs[16][132];
    const int bx = blockIdx.x;
    const int mt = bx >> 3, nt = bx & 7;
    const int m0 = mt * 128, n0 = nt * 128;
    const int tid = threadIdx.x;
    const int ty = tid >> 4, tx = tid & 15;
    const float* Bsrc = (n0 < 512) ? (Wqk + n0) : (Wv + (n0 - 512));
    const int ar0 = tid >> 2, acq = (tid & 3) * 4;
    const int ar1 = 64 + (tid >> 2);
    const int bk0 = tid >> 5, bnq = (tid & 31) * 4;
    const int bk1 = 8 + (tid >> 5);
    const float* Aptr0 = Q + (size_t)(m0 + ar0) * 512 + acq;
    const float* Aptr1 = Q + (size_t)(m0 + ar1) * 512 + acq;
    const float* Bptr0 = Bsrc + (size_t)bk0 * 512 + bnq;
    const float* Bptr1 = Bsrc + (size_t)bk1 * 512 + bnq;
    float acc[8][8] = {};
    float4 a0 = *(const float4*)(Aptr0);
    float4 a1 = *(const float4*)(Aptr1);
    float4 b0 = *(const float4*)(Bptr0);
    float4 b1 = *(const float4*)(Bptr1);
    for (int k0 = 0; k0 < 512; k0 += 16) {
        As[acq+0][ar0]=a0.x; As[acq+1][ar0]=a0.y; As[acq+2][ar0]=a0.z; As[acq+3][ar0]=a0.w;
        As[acq+0][ar1]=a1.x; As[acq+1][ar1]=a1.y; As[acq+2][ar1]=a1.z; As[acq+3][ar1]=a1.w;
        *(float4*)&Bs[bk0][bnq] = b0;
        *(float4*)&Bs[bk1][bnq] = b1;
        __syncthreads();
        if (k0 + 16 < 512) {
            a0 = *(const float4*)(Aptr0 + k0 + 16);
            a1 = *(const float4*)(Aptr1 + k0 + 16);
            b0 = *(const float4*)(Bptr0 + (size_t)(k0 + 16) * 512);
            b1 = *(const float4*)(Bptr1 + (size_t)(k0 + 16) * 512);
        }
        #pragma unroll
        for (int kk = 0; kk < 16; kk++) {
            float a_[8], b_[8];
            *(float4*)&a_[0] = *(float4*)&As[kk][ty*4];
            *(float4*)&a_[4] = *(float4*)&As[kk][64 + ty*4];
            *(float4*)&b_[0] = *(float4*)&Bs[kk][tx*4];
            *(float4*)&b_[4] = *(float4*)&Bs[kk][64 + tx*4];
            #pragma unroll
            for (int i = 0; i < 8; i++)
                #pragma unroll
                for (int j = 0; j < 8; j++)
                    acc[i][j] += a_[i] * b_[j];
        }
        __syncthreads();
    }
    #pragma unroll
    for (int ig = 0; ig < 2; ig++) {
        #pragma unroll
        for (int i = 0; i < 4; i++) {
            int row = m0 + ig*64 + ty*4 + i;
            int b = row >> 11, t = row & 2047;
            #pragma unroll
            for (int jg = 0; jg < 2; jg++) {
                int n = n0 + jg*64 + tx*4;
                float4 r4 = make_float4(acc[ig*4+i][jg*4+0], acc[ig*4+i][jg*4+1],
                                        acc[ig*4+i][jg*4+2], acc[ig*4+i][jg*4+3]);
                if (n < 512) {
                    *(float4*)(qk + ((size_t)((b*8 + (n>>6))*2048 + t))*64 + (n&63)) = r4;
                } else {
                    int nv = n - 512;
                    *(float4*)(vv + ((size_t)((b*8 + (nv>>6))*2048 + t))*64 + (nv&63)) = r4;
                }
            }
        }
    }
    // ---- fused rnorm: this block owns complete 64-dim vectors for 2 heads x 128 tokens ----
    if (n0 < 512) {
        #pragma unroll
        for (int jg = 0; jg < 2; jg++) {
            int h = (n0 + jg*64) >> 6;
            #pragma unroll
            for (int ig = 0; ig < 2; ig++) {
                #pragma unroll
                for (int i = 0; i < 4; i++) {
                    float s = acc[ig*4+i][jg*4+0]*acc[ig*4+i][jg*4+0]
                            + acc[ig*4+i][jg*4+1]*acc[ig*4+i][jg*4+1]
                            + acc[ig*4+i][jg*4+2]*acc[ig*4+i][jg*4+2]
                            + acc[ig*4+i][jg*4+3]*acc[ig*4+i][jg*4+3];
                    s += __shfl_xor(s, 1);
                    s += __shfl_xor(s, 2);
                    s += __shfl_xor(s, 4);
                    s += __shfl_xor(s, 8);
                    if (tx == 0) {
                        int row = m0 + ig*64 + ty*4 + i;
                        int b = row >> 11, t = row & 2047;
                        rnorm[((size_t)(b*8 + h))*2048 + t] = 1.0f / fmaxf(sqrtf(s), 1e-12f);
                    }
                }
            }
        }
    }
}

// ---------------- K2: hash = f32 GEMM (128 tokens, K=64) + signed argmax ----------------
// FROZEN round-6 body (287 us, VGPR 64, VALUBusy 70%).
__global__ __launch_bounds__(256) void k_hash(const float* __restrict__ qk,
    const float* __restrict__ rotT2, unsigned* __restrict__ buckets)
{
    __shared__ float As[64*128];    // As[k][row], pitch 128 (32 KB)
    const int bx = blockIdx.x;
    const int bm = bx >> 4;
    const int row0 = (bx & 15) << 7;             // token base within bm
    const int tid = threadIdx.x;
    const int ty = tid >> 4, tx = tid & 15;
    // ---- stage A (128 tokens x 64 k), transposed ----
    {
        const int r = tid >> 1;
        const int kb = (tid & 1) * 8;            // float4 units
        const float* src = qk + ((size_t)(bm*2048 + row0 + r))*64;
        #pragma unroll
        for (int c = 0; c < 8; c++) {
            float4 a4 = *(const float4*)(src + (size_t)(kb + c)*4);
            int k = (kb + c)*4;
            As[(k+0)*128 + r] = a4.x;
            As[(k+1)*128 + r] = a4.y;
            As[(k+2)*128 + r] = a4.z;
            As[(k+3)*128 + r] = a4.w;
        }
    }
    __syncthreads();
    #pragma unroll 1
    for (int h = 0; h < 4; h++) {
        float bv[8]; unsigned bi[8];
        #pragma unroll
        for (int i = 0; i < 8; i++) { bv[i] = -3.402823466e38f; bi[i] = 0u; }
        #pragma unroll 1
        for (int ch = 0; ch < 4; ch++) {
            const float* bsrc = rotT2 + (size_t)h*16384 + ch*64 + tx*4;
            float acc[8][4] = {};
            #pragma unroll 16
            for (int kk = 0; kk < 64; kk++) {
                float4 b4 = *(const float4*)(bsrc + (size_t)kk*256);
                float a_[8];
                *(float4*)&a_[0] = *(float4*)&As[kk*128 + ty*4];
                *(float4*)&a_[4] = *(float4*)&As[kk*128 + 64 + ty*4];
                float b_[4] = {b4.x, b4.y, b4.z, b4.w};
                #pragma unroll
                for (int i = 0; i < 8; i++)
                    #pragma unroll
                    for (int j = 0; j < 4; j++)
                        acc[i][j] += a_[i] * b_[j];
            }
            #pragma unroll
            for (int j = 0; j < 4; j++) {
                unsigned c0 = (unsigned)(ch*64 + tx*4 + j);
                unsigned nc0 = 256u + c0;
                #pragma unroll
                for (int i = 0; i < 8; i++) {
                    float v = acc[i][j];
                    if (v > bv[i] || (v == bv[i] && c0 < bi[i])) { bv[i] = v; bi[i] = c0; }
                    float nv = -v;
                    if (nv > bv[i] || (nv == bv[i] && nc0 < bi[i])) { bv[i] = nv; bi[i] = nc0; }
                }
            }
        }
        #pragma unroll
        for (int i = 0; i < 8; i++) {
            #pragma unroll
            for (int d = 1; d < 16; d <<= 1) {
                float ov = __shfl_xor(bv[i], d);
                unsigned oi = (unsigned)__shfl_xor((int)bi[i], d);
                if (ov > bv[i] || (ov == bv[i] && oi < bi[i])) { bv[i] = ov; bi[i] = oi; }
            }
        }
        if (tx == 0) {
            #pragma unroll
            for (int i = 0; i < 8; i++) {
                int r = (i < 4) ? (ty*4 + i) : (64 + ty*4 + (i - 4));
                buckets[((size_t)(bm*4 + h))*2048 + row0 + r] = bi[i];
            }
        }
    }
}

// ---------------- K3: stable counting sort per (bm,hash) ----------------
__global__ __launch_bounds__(256) void k_sort(const unsigned* __restrict__ buckets,
                                              unsigned* __restrict__ st)
{
    __shared__ unsigned whist[4][512];
    __shared__ unsigned baseb[512];
    const int seg = blockIdx.x;                  // bm*4+h
    const unsigned* bk = buckets + (size_t)seg * 2048;
    unsigned* out = st + (size_t)seg * 2048;
    const int tid = threadIdx.x, w = tid >> 6, lane = tid & 63;
    for (int b = tid; b < 2048; b += 256) ((unsigned*)whist)[b] = 0u;
    __syncthreads();
    unsigned myb[8];
    #pragma unroll
    for (int r = 0; r < 8; r++) {
        int pos = w*512 + r*64 + lane;
        myb[r] = bk[pos];
        atomicAdd(&whist[w][myb[r]], 1u);
    }
    __syncthreads();
    for (int b = tid; b < 512; b += 256) {
        unsigned p = 0;
        #pragma unroll
        for (int ww = 0; ww < 4; ww++) { unsigned t = whist[ww][b]; whist[ww][b] = p; p += t; }
        baseb[b] = p;
    }
    __syncthreads();
    if (tid == 0) {
        unsigned run = 0;
        for (int b = 0; b < 512; b++) { unsigned t = baseb[b]; baseb[b] = run; run += t; }
    }
    __syncthreads();
    for (int b = tid; b < 512; b += 256) {
        unsigned bb = baseb[b];
        #pragma unroll
        for (int ww = 0; ww < 4; ww++) whist[ww][b] += bb;
    }
    __syncthreads();
    for (int r = 0; r < 8; r++) {
        unsigned b = myb[r];
        int pos = w*512 + r*64 + lane;
        unsigned base = whist[w][b];             // read before this round's bumps
        unsigned rank = 0;
        for (int j = 0; j < 64; j++) {
            unsigned bj = __shfl(b, j);
            rank += (j < lane && bj == b) ? 1u : 0u;
        }
        out[base + rank] = (unsigned)pos;
        atomicAdd(&whist[w][b], 1u);
    }
}

// ---------------- K4: chunked LSH attention (bf16 oh output) ----------------
__global__ __launch_bounds__(256) void k_attn(const float* __restrict__ qk,
    const float* __restrict__ vv, const float* __restrict__ rnorm,
    const unsigned* __restrict__ st, unsigned short* __restrict__ oh16,
    float* __restrict__ logits)
{
    __shared__ float qs[68][68];
    __shared__ float vs[68][68];
    __shared__ unsigned P[68];
    __shared__ float rn[68];
    const int sid = blockIdx.x;
    const int stripi = sid & 31;
    const int seg = sid >> 5;
    const int bm = seg >> 2, h = seg & 3;
    const int G0 = (h*512 + stripi*16) * 4;      // first q slot (global, 0..8191)
    const int tid = threadIdx.x;
    for (int j = tid; j < 68; j += 256) {
        int G = (G0 - 4 + j) & 8191;
        int hg = G >> 11, sg = G & 2047;
        unsigned tok = st[((size_t)(bm*4 + hg))*2048 + sg];
        P[j] = tok;
        rn[j] = rnorm[bm*2048 + (int)tok];
    }
    __syncthreads();
    for (int e = tid; e < 68*16; e += 256) {
        int j = e >> 4, fq = e & 15;
        unsigned tok = P[j];
        size_t base = ((size_t)(bm*2048 + (int)tok))*64 + fq*4;
        *(float4*)&qs[j][fq*4] = *(const float4*)(qk + base);
        *(float4*)&vs[j][fq*4] = *(const float4*)(vv + base);
    }
    __syncthreads();
    const int w = tid >> 6, lane = tid & 63;
    const int half = lane >> 5, qi = (lane >> 3) & 3, jj = lane & 7;
    const int fb = lane & 7;
    for (int cp = 0; cp < 2; cp++) {
        int c = w*4 + cp*2 + half;               // local chunk 0..15
        int jq = 4 + c*4 + qi;
        int jk = c*4 + jj;
        float dot = 0.f;
        #pragma unroll
        for (int fq = 0; fq < 16; fq++) {
            float4 q4 = *(float4*)&qs[jq][fq*4];
            float4 k4 = *(float4*)&qs[jk][fq*4];
            dot += q4.x*k4.x + q4.y*k4.y + q4.z*k4.z + q4.w*k4.w;
        }
        dot *= 0.125f * rn[jk];
        if (P[jq] == P[jk]) dot = SELF_VAL;
        float m = dot;
        m = fmaxf(m, __shfl_xor(m, 1));
        m = fmaxf(m, __shfl_xor(m, 2));
        m = fmaxf(m, __shfl_xor(m, 4));
        float ex = expf(dot - m);
        float s = ex;
        s += __shfl_xor(s, 1); s += __shfl_xor(s, 2); s += __shfl_xor(s, 4);
        float lse = m + logf(s);
        float p = expf(dot - lse);
        unsigned tq = P[jq];
        if (jj == 0) logits[((size_t)(bm*4 + h))*2048 + tq] = lse;
        float a0=0,a1=0,a2=0,a3=0,a4a=0,a5=0,a6=0,a7=0;
        #pragma unroll
        for (int j2 = 0; j2 < 8; j2++) {
            float pj = __shfl(p, (lane & 0x38) | j2);
            float4 va = *(float4*)&vs[c*4 + j2][fb*8];
            float4 vb = *(float4*)&vs[c*4 + j2][fb*8 + 4];
            a0 += pj*va.x; a1 += pj*va.y; a2 += pj*va.z; a3 += pj*va.w;
            a4a += pj*vb.x; a5 += pj*vb.y; a6 += pj*vb.z; a7 += pj*vb.w;
        }
        union { unsigned short s[8]; uint4 v; } ob;
        ob.s[0]=f2bf(a0); ob.s[1]=f2bf(a1); ob.s[2]=f2bf(a2); ob.s[3]=f2bf(a3);
        ob.s[4]=f2bf(a4a); ob.s[5]=f2bf(a5); ob.s[6]=f2bf(a6); ob.s[7]=f2bf(a7);
        *(uint4*)(oh16 + ((size_t)((bm*4 + h)*2048 + (int)tq))*64 + fb*8) = ob.v;
    }
}

// ---------------- K5: combine hash rounds (bf16 oh input) ----------------
__global__ __launch_bounds__(256) void k_combine(const unsigned short* __restrict__ oh16,
    const float* __restrict__ logits, float* __restrict__ comb)
{
    int w = threadIdx.x >> 6, lane = threadIdx.x & 63;
    int row = blockIdx.x * 4 + w;                // bm*2048+t
    int bm = row >> 11, t = row & 2047;
    int b = bm >> 3, head = bm & 7;
    float l0 = logits[((size_t)(bm*4 + 0))*2048 + t];
    float l1 = logits[((size_t)(bm*4 + 1))*2048 + t];
    float l2 = logits[((size_t)(bm*4 + 2))*2048 + t];
    float l3 = logits[((size_t)(bm*4 + 3))*2048 + t];
    float m = fmaxf(fmaxf(l0, l1), fmaxf(l2, l3));
    float e0 = expf(l0 - m), e1 = expf(l1 - m), e2 = expf(l2 - m), e3 = expf(l3 - m);
    float inv = 1.0f / (e0 + e1 + e2 + e3);
    float o = 0.f;
    o += (e0*inv) * bf2f(oh16[((size_t)((bm*4+0)*2048 + t))*64 + lane]);
    o += (e1*inv) * bf2f(oh16[((size_t)((bm*4+1)*2048 + t))*64 + lane]);
    o += (e2*inv) * bf2f(oh16[((size_t)((bm*4+2)*2048 + t))*64 + lane]);
    o += (e3*inv) * bf2f(oh16[((size_t)((bm*4+3)*2048 + t))*64 + lane]);
    comb[((size_t)(b*2048 + t))*512 + head*64 + lane] = o;
}

// ---------------- K6: output GEMM + bias (f32, 128x128, 8x8/thread, T14 dbuf) ----------------
__global__ __launch_bounds__(256) void k_gemm_out(
    const float* __restrict__ A, const float* __restrict__ Wout,
    const float* __restrict__ bias, float* __restrict__ out)
{
    __shared__ float As[16][132];
    __shared__ float Bs[16][132];
    const int bx = blockIdx.x;
    const int mt = bx >> 2, nt = bx & 3;
    const int m0 = mt * 128, n0 = nt * 128;
    const int tid = threadIdx.x;
    const int ty = tid >> 4, tx = tid & 15;
    const int ar0 = tid >> 2, acq = (tid & 3) * 4;
    const int ar1 = 64 + (tid >> 2);
    const int bk0 = tid >> 5, bnq = (tid & 31) * 4;
    const int bk1 = 8 + (tid >> 5);
    const float* Aptr0 = A + (size_t)(m0 + ar0) * 512 + acq;
    const float* Aptr1 = A + (size_t)(m0 + ar1) * 512 + acq;
    const float* Bptr0 = Wout + (size_t)bk0 * 512 + n0 + bnq;
    const float* Bptr1 = Wout + (size_t)bk1 * 512 + n0 + bnq;
    float acc[8][8] = {};
    float4 a0 = *(const float4*)(Aptr0);
    float4 a1 = *(const float4*)(Aptr1);
    float4 b0 = *(const float4*)(Bptr0);
    float4 b1 = *(const float4*)(Bptr1);
    for (int k0 = 0; k0 < 512; k0 += 16) {
        As[acq+0][ar0]=a0.x; As[acq+1][ar0]=a0.y; As[acq+2][ar0]=a0.z; As[acq+3][ar0]=a0.w;
        As[acq+0][ar1]=a1.x; As[acq+1][ar1]=a1.y; As[acq+2][ar1]=a1.z; As[acq+3][ar1]=a1.w;
        *(float4*)&Bs[bk0][bnq] = b0;
        *(float4*)&Bs[bk1][bnq] = b1;
        __syncthreads();
        if (k0 + 16 < 512) {
            a0 = *(const float4*)(Aptr0 + k0 + 16);
            a1 = *(const float4*)(Aptr1 + k0 + 16);
            b0 = *(const float4*)(Bptr0 + (size_t)(k0 + 16) * 512);
            b1 = *(const float4*)(Bptr1 + (size_t)(k0 + 16) * 512);
        }
        #pragma unroll
        for (int kk = 0; kk < 16; kk++) {
            float a_[8], b_[8];
            *(float4*)&a_[0] = *(float4*)&As[kk][ty*4];
            *(float4*)&a_[4] = *(float4*)&As[kk][64 + ty*4];
            *(float4*)&b_[0] = *(float4*)&Bs[kk][tx*4];
            *(float4*)&b_[4] = *(float4*)&Bs[kk][64 + tx*4];
            #pragma unroll
            for (int i = 0; i < 8; i++)
                #pragma unroll
                for (int j = 0; j < 8; j++)
                    acc[i][j] += a_[i] * b_[j];
        }
        __syncthreads();
    }
    #pragma unroll
    for (int ig = 0; ig < 2; ig++) {
        #pragma unroll
        for (int i = 0; i < 4; i++) {
            int row = m0 + ig*64 + ty*4 + i;
            #pragma unroll
            for (int jg = 0; jg < 2; jg++) {
                int n = n0 + jg*64 + tx*4;
                float4 bb = *(const float4*)(bias + n);
                float4 r4 = make_float4(acc[ig*4+i][jg*4+0] + bb.x, acc[ig*4+i][jg*4+1] + bb.y,
                                        acc[ig*4+i][jg*4+2] + bb.z, acc[ig*4+i][jg*4+3] + bb.w);
                *(float4*)(out + (size_t)row * 512 + n) = r4;
            }
        }
    }
}

extern "C" void kernel_launch(void* const* d_in, const int* in_sizes, int n_in,
                              void* d_out, int out_size, void* d_ws, size_t ws_size,
                              hipStream_t stream)
{
    const float* Q    = (const float*)d_in[0];
    const float* Wqk  = (const float*)d_in[3];
    const float* Wv   = (const float*)d_in[4];
    const float* Wout = (const float*)d_in[5];
    const float* bout = (const float*)d_in[6];
    const float* rot  = (const float*)d_in[7];
    float* ws = (float*)d_ws;
    float* qk     = ws;                       // 8,388,608 floats
    float* vv     = ws + 8388608;             // 8,388,608
    unsigned short* oh16 = (unsigned short*)(ws + 16777216);  // 33.5M ushort
    float* comb   = ws + 50331648;            // 8,388,608
    float* rnorm  = ws + 58720256;            // 131,072
    float* logits = ws + 58851328;            // 524,288
    unsigned* buckets = (unsigned*)(ws + 59375616);   // 524,288
    unsigned* st      = (unsigned*)(ws + 59899904);   // 524,288
    float* rotT2  = ws + 60424192;            // 65,536
    float* out = (float*)d_out;

    k_rotT    <<<dim3(256),  dim3(256), 0, stream>>>(rot, rotT2);
    k_gemm_qkv<<<dim3(1024), dim3(256), 0, stream>>>(Q, Wqk, Wv, qk, vv, rnorm);
    k_hash    <<<dim3(1024), dim3(256), 0, stream>>>(qk, rotT2, buckets);
    k_sort    <<<dim3(256),  dim3(256), 0, stream>>>(buckets, st);
    k_attn    <<<dim3(8192), dim3(256), 0, stream>>>(qk, vv, rnorm, st, oh16, logits);
    k_combine <<<dim3(32768),dim3(256), 0, stream>>>(oh16, logits, comb);
    k_gemm_out<<<dim3(512),  dim3(256), 0, stream>>>(comb, Wout, bout, out);
}

// Round 16
// 619.348 us; speedup vs baseline: 1.4671x; 1.1435x over previous
//
#include <hip/hip_runtime.h>
#include <math.h>

#define SELF_VAL (-5e4f)

typedef __attribute__((ext_vector_type(8))) short bf16x8;
typedef __attribute__((ext_vector_type(4))) float f32x4;

__device__ __forceinline__ unsigned short f2bf(float x) {
    unsigned b = __float_as_uint(x);
    b += 0x7FFFu + ((b >> 16) & 1u);
    return (unsigned short)(b >> 16);
}
__device__ __forceinline__ float bf2f(unsigned short h) {
    return __uint_as_float(((unsigned)h) << 16);
}

// ---------------- K0: re-layout rotations -> rotT2[h][k][col]  (4 x 64 x 256) ----------------
__global__ __launch_bounds__(256) void k_rotT(const float* __restrict__ rot,
                                              float* __restrict__ rotT2)
{
    int idx = blockIdx.x * 256 + threadIdx.x;    // 0..65535
    int h = idx >> 14, k = (idx >> 8) & 63, col = idx & 255;
    rotT2[idx] = rot[k * 1024 + h * 256 + col];
}

// ---------------- K0b: Wout -> transposed bf16 WoutT16[n][k] ----------------
__global__ __launch_bounds__(256) void k_woutT(const float* __restrict__ Wout,
                                               unsigned short* __restrict__ WoutT16)
{
    int idx = blockIdx.x * 256 + threadIdx.x;    // 0..262143
    int n = idx >> 9, k = idx & 511;
    WoutT16[idx] = f2bf(Wout[(size_t)k * 512 + n]);
}

// ---------------- K1: fused qk/v GEMM (f32, 128x128, 8x8/thread, T14 dbuf) ----------------
// + fused rnorm epilogue for qk blocks (n0 < 512).
__global__ __launch_bounds__(256) void k_gemm_qkv(
    const float* __restrict__ Q, const float* __restrict__ Wqk,
    const float* __restrict__ Wv, float* __restrict__ qk, float* __restrict__ vv,
    float* __restrict__ rnorm)
{
    __shared__ float As[16][132];   // transposed: As[k][m]
    __shared__ float Bs[16][132];
    const int bx = blockIdx.x;
    const int mt = bx >> 3, nt = bx & 7;
    const int m0 = mt * 128, n0 = nt * 128;
    const int tid = threadIdx.x;
    const int ty = tid >> 4, tx = tid & 15;
    const float* Bsrc = (n0 < 512) ? (Wqk + n0) : (Wv + (n0 - 512));
    const int ar0 = tid >> 2, acq = (tid & 3) * 4;
    const int ar1 = 64 + (tid >> 2);
    const int bk0 = tid >> 5, bnq = (tid & 31) * 4;
    const int bk1 = 8 + (tid >> 5);
    const float* Aptr0 = Q + (size_t)(m0 + ar0) * 512 + acq;
    const float* Aptr1 = Q + (size_t)(m0 + ar1) * 512 + acq;
    const float* Bptr0 = Bsrc + (size_t)bk0 * 512 + bnq;
    const float* Bptr1 = Bsrc + (size_t)bk1 * 512 + bnq;
    float acc[8][8] = {};
    float4 a0 = *(const float4*)(Aptr0);
    float4 a1 = *(const float4*)(Aptr1);
    float4 b0 = *(const float4*)(Bptr0);
    float4 b1 = *(const float4*)(Bptr1);
    for (int k0 = 0; k0 < 512; k0 += 16) {
        As[acq+0][ar0]=a0.x; As[acq+1][ar0]=a0.y; As[acq+2][ar0]=a0.z; As[acq+3][ar0]=a0.w;
        As[acq+0][ar1]=a1.x; As[acq+1][ar1]=a1.y; As[acq+2][ar1]=a1.z; As[acq+3][ar1]=a1.w;
        *(float4*)&Bs[bk0][bnq] = b0;
        *(float4*)&Bs[bk1][bnq] = b1;
        __syncthreads();
        if (k0 + 16 < 512) {
            a0 = *(const float4*)(Aptr0 + k0 + 16);
            a1 = *(const float4*)(Aptr1 + k0 + 16);
            b0 = *(const float4*)(Bptr0 + (size_t)(k0 + 16) * 512);
            b1 = *(const float4*)(Bptr1 + (size_t)(k0 + 16) * 512);
        }
        #pragma unroll
        for (int kk = 0; kk < 16; kk++) {
            float a_[8], b_[8];
            *(float4*)&a_[0] = *(float4*)&As[kk][ty*4];
            *(float4*)&a_[4] = *(float4*)&As[kk][64 + ty*4];
            *(float4*)&b_[0] = *(float4*)&Bs[kk][tx*4];
            *(float4*)&b_[4] = *(float4*)&Bs[kk][64 + tx*4];
            #pragma unroll
            for (int i = 0; i < 8; i++)
                #pragma unroll
                for (int j = 0; j < 8; j++)
                    acc[i][j] += a_[i] * b_[j];
        }
        __syncthreads();
    }
    #pragma unroll
    for (int ig = 0; ig < 2; ig++) {
        #pragma unroll
        for (int i = 0; i < 4; i++) {
            int row = m0 + ig*64 + ty*4 + i;
            int b = row >> 11, t = row & 2047;
            #pragma unroll
            for (int jg = 0; jg < 2; jg++) {
                int n = n0 + jg*64 + tx*4;
                float4 r4 = make_float4(acc[ig*4+i][jg*4+0], acc[ig*4+i][jg*4+1],
                                        acc[ig*4+i][jg*4+2], acc[ig*4+i][jg*4+3]);
                if (n < 512) {
                    *(float4*)(qk + ((size_t)((b*8 + (n>>6))*2048 + t))*64 + (n&63)) = r4;
                } else {
                    int nv = n - 512;
                    *(float4*)(vv + ((size_t)((b*8 + (nv>>6))*2048 + t))*64 + (nv&63)) = r4;
                }
            }
        }
    }
    // ---- fused rnorm ----
    if (n0 < 512) {
        #pragma unroll
        for (int jg = 0; jg < 2; jg++) {
            int h = (n0 + jg*64) >> 6;
            #pragma unroll
            for (int ig = 0; ig < 2; ig++) {
                #pragma unroll
                for (int i = 0; i < 4; i++) {
                    float s = acc[ig*4+i][jg*4+0]*acc[ig*4+i][jg*4+0]
                            + acc[ig*4+i][jg*4+1]*acc[ig*4+i][jg*4+1]
                            + acc[ig*4+i][jg*4+2]*acc[ig*4+i][jg*4+2]
                            + acc[ig*4+i][jg*4+3]*acc[ig*4+i][jg*4+3];
                    s += __shfl_xor(s, 1);
                    s += __shfl_xor(s, 2);
                    s += __shfl_xor(s, 4);
                    s += __shfl_xor(s, 8);
                    if (tx == 0) {
                        int row = m0 + ig*64 + ty*4 + i;
                        int b = row >> 11, t = row & 2047;
                        rnorm[((size_t)(b*8 + h))*2048 + t] = 1.0f / fmaxf(sqrtf(s), 1e-12f);
                    }
                }
            }
        }
    }
}

// ---------------- K2: hash = f32 GEMM (128 tokens, K=64) + signed argmax ----------------
// FROZEN round-6 body (287 us, VGPR 64, VALUBusy 70%).
__global__ __launch_bounds__(256) void k_hash(const float* __restrict__ qk,
    const float* __restrict__ rotT2, unsigned* __restrict__ buckets)
{
    __shared__ float As[64*128];    // As[k][row], pitch 128 (32 KB)
    const int bx = blockIdx.x;
    const int bm = bx >> 4;
    const int row0 = (bx & 15) << 7;             // token base within bm
    const int tid = threadIdx.x;
    const int ty = tid >> 4, tx = tid & 15;
    {
        const int r = tid >> 1;
        const int kb = (tid & 1) * 8;            // float4 units
        const float* src = qk + ((size_t)(bm*2048 + row0 + r))*64;
        #pragma unroll
        for (int c = 0; c < 8; c++) {
            float4 a4 = *(const float4*)(src + (size_t)(kb + c)*4);
            int k = (kb + c)*4;
            As[(k+0)*128 + r] = a4.x;
            As[(k+1)*128 + r] = a4.y;
            As[(k+2)*128 + r] = a4.z;
            As[(k+3)*128 + r] = a4.w;
        }
    }
    __syncthreads();
    #pragma unroll 1
    for (int h = 0; h < 4; h++) {
        float bv[8]; unsigned bi[8];
        #pragma unroll
        for (int i = 0; i < 8; i++) { bv[i] = -3.402823466e38f; bi[i] = 0u; }
        #pragma unroll 1
        for (int ch = 0; ch < 4; ch++) {
            const float* bsrc = rotT2 + (size_t)h*16384 + ch*64 + tx*4;
            float acc[8][4] = {};
            #pragma unroll 16
            for (int kk = 0; kk < 64; kk++) {
                float4 b4 = *(const float4*)(bsrc + (size_t)kk*256);
                float a_[8];
                *(float4*)&a_[0] = *(float4*)&As[kk*128 + ty*4];
                *(float4*)&a_[4] = *(float4*)&As[kk*128 + 64 + ty*4];
                float b_[4] = {b4.x, b4.y, b4.z, b4.w};
                #pragma unroll
                for (int i = 0; i < 8; i++)
                    #pragma unroll
                    for (int j = 0; j < 4; j++)
                        acc[i][j] += a_[i] * b_[j];
            }
            #pragma unroll
            for (int j = 0; j < 4; j++) {
                unsigned c0 = (unsigned)(ch*64 + tx*4 + j);
                unsigned nc0 = 256u + c0;
                #pragma unroll
                for (int i = 0; i < 8; i++) {
                    float v = acc[i][j];
                    if (v > bv[i] || (v == bv[i] && c0 < bi[i])) { bv[i] = v; bi[i] = c0; }
                    float nv = -v;
                    if (nv > bv[i] || (nv == bv[i] && nc0 < bi[i])) { bv[i] = nv; bi[i] = nc0; }
                }
            }
        }
        #pragma unroll
        for (int i = 0; i < 8; i++) {
            #pragma unroll
            for (int d = 1; d < 16; d <<= 1) {
                float ov = __shfl_xor(bv[i], d);
                unsigned oi = (unsigned)__shfl_xor((int)bi[i], d);
                if (ov > bv[i] || (ov == bv[i] && oi < bi[i])) { bv[i] = ov; bi[i] = oi; }
            }
        }
        if (tx == 0) {
            #pragma unroll
            for (int i = 0; i < 8; i++) {
                int r = (i < 4) ? (ty*4 + i) : (64 + ty*4 + (i - 4));
                buckets[((size_t)(bm*4 + h))*2048 + row0 + r] = bi[i];
            }
        }
    }
}

// ---------------- K3: stable counting sort per (bm,hash) ----------------
__global__ __launch_bounds__(256) void k_sort(const unsigned* __restrict__ buckets,
                                              unsigned* __restrict__ st)
{
    __shared__ unsigned whist[4][512];
    __shared__ unsigned baseb[512];
    const int seg = blockIdx.x;                  // bm*4+h
    const unsigned* bk = buckets + (size_t)seg * 2048;
    unsigned* out = st + (size_t)seg * 2048;
    const int tid = threadIdx.x, w = tid >> 6, lane = tid & 63;
    for (int b = tid; b < 2048; b += 256) ((unsigned*)whist)[b] = 0u;
    __syncthreads();
    unsigned myb[8];
    #pragma unroll
    for (int r = 0; r < 8; r++) {
        int pos = w*512 + r*64 + lane;
        myb[r] = bk[pos];
        atomicAdd(&whist[w][myb[r]], 1u);
    }
    __syncthreads();
    for (int b = tid; b < 512; b += 256) {
        unsigned p = 0;
        #pragma unroll
        for (int ww = 0; ww < 4; ww++) { unsigned t = whist[ww][b]; whist[ww][b] = p; p += t; }
        baseb[b] = p;
    }
    __syncthreads();
    if (tid == 0) {
        unsigned run = 0;
        for (int b = 0; b < 512; b++) { unsigned t = baseb[b]; baseb[b] = run; run += t; }
    }
    __syncthreads();
    for (int b = tid; b < 512; b += 256) {
        unsigned bb = baseb[b];
        #pragma unroll
        for (int ww = 0; ww < 4; ww++) whist[ww][b] += bb;
    }
    __syncthreads();
    for (int r = 0; r < 8; r++) {
        unsigned b = myb[r];
        int pos = w*512 + r*64 + lane;
        unsigned base = whist[w][b];             // read before this round's bumps
        unsigned rank = 0;
        for (int j = 0; j < 64; j++) {
            unsigned bj = __shfl(b, j);
            rank += (j < lane && bj == b) ? 1u : 0u;
        }
        out[base + rank] = (unsigned)pos;
        atomicAdd(&whist[w][b], 1u);
    }
}

// ---------------- K4: chunked LSH attention (bf16 oh output) ----------------
__global__ __launch_bounds__(256) void k_attn(const float* __restrict__ qk,
    const float* __restrict__ vv, const float* __restrict__ rnorm,
    const unsigned* __restrict__ st, unsigned short* __restrict__ oh16,
    float* __restrict__ logits)
{
    __shared__ float qs[68][68];
    __shared__ float vs[68][68];
    __shared__ unsigned P[68];
    __shared__ float rn[68];
    const int sid = blockIdx.x;
    const int stripi = sid & 31;
    const int seg = sid >> 5;
    const int bm = seg >> 2, h = seg & 3;
    const int G0 = (h*512 + stripi*16) * 4;      // first q slot (global, 0..8191)
    const int tid = threadIdx.x;
    for (int j = tid; j < 68; j += 256) {
        int G = (G0 - 4 + j) & 8191;
        int hg = G >> 11, sg = G & 2047;
        unsigned tok = st[((size_t)(bm*4 + hg))*2048 + sg];
        P[j] = tok;
        rn[j] = rnorm[bm*2048 + (int)tok];
    }
    __syncthreads();
    for (int e = tid; e < 68*16; e += 256) {
        int j = e >> 4, fq = e & 15;
        unsigned tok = P[j];
        size_t base = ((size_t)(bm*2048 + (int)tok))*64 + fq*4;
        *(float4*)&qs[j][fq*4] = *(const float4*)(qk + base);
        *(float4*)&vs[j][fq*4] = *(const float4*)(vv + base);
    }
    __syncthreads();
    const int w = tid >> 6, lane = tid & 63;
    const int half = lane >> 5, qi = (lane >> 3) & 3, jj = lane & 7;
    const int fb = lane & 7;
    for (int cp = 0; cp < 2; cp++) {
        int c = w*4 + cp*2 + half;               // local chunk 0..15
        int jq = 4 + c*4 + qi;
        int jk = c*4 + jj;
        float dot = 0.f;
        #pragma unroll
        for (int fq = 0; fq < 16; fq++) {
            float4 q4 = *(float4*)&qs[jq][fq*4];
            float4 k4 = *(float4*)&qs[jk][fq*4];
            dot += q4.x*k4.x + q4.y*k4.y + q4.z*k4.z + q4.w*k4.w;
        }
        dot *= 0.125f * rn[jk];
        if (P[jq] == P[jk]) dot = SELF_VAL;
        float m = dot;
        m = fmaxf(m, __shfl_xor(m, 1));
        m = fmaxf(m, __shfl_xor(m, 2));
        m = fmaxf(m, __shfl_xor(m, 4));
        float ex = expf(dot - m);
        float s = ex;
        s += __shfl_xor(s, 1); s += __shfl_xor(s, 2); s += __shfl_xor(s, 4);
        float lse = m + logf(s);
        float p = expf(dot - lse);
        unsigned tq = P[jq];
        if (jj == 0) logits[((size_t)(bm*4 + h))*2048 + tq] = lse;
        float a0=0,a1=0,a2=0,a3=0,a4a=0,a5=0,a6=0,a7=0;
        #pragma unroll
        for (int j2 = 0; j2 < 8; j2++) {
            float pj = __shfl(p, (lane & 0x38) | j2);
            float4 va = *(float4*)&vs[c*4 + j2][fb*8];
            float4 vb = *(float4*)&vs[c*4 + j2][fb*8 + 4];
            a0 += pj*va.x; a1 += pj*va.y; a2 += pj*va.z; a3 += pj*va.w;
            a4a += pj*vb.x; a5 += pj*vb.y; a6 += pj*vb.z; a7 += pj*vb.w;
        }
        union { unsigned short s[8]; uint4 v; } ob;
        ob.s[0]=f2bf(a0); ob.s[1]=f2bf(a1); ob.s[2]=f2bf(a2); ob.s[3]=f2bf(a3);
        ob.s[4]=f2bf(a4a); ob.s[5]=f2bf(a5); ob.s[6]=f2bf(a6); ob.s[7]=f2bf(a7);
        *(uint4*)(oh16 + ((size_t)((bm*4 + h)*2048 + (int)tq))*64 + fb*8) = ob.v;
    }
}

// ---------------- K5: combine hash rounds (bf16 in, bf16 out) ----------------
__global__ __launch_bounds__(256) void k_combine(const unsigned short* __restrict__ oh16,
    const float* __restrict__ logits, unsigned short* __restrict__ comb16)
{
    int w = threadIdx.x >> 6, lane = threadIdx.x & 63;
    int row = blockIdx.x * 4 + w;                // bm*2048+t
    int bm = row >> 11, t = row & 2047;
    int b = bm >> 3, head = bm & 7;
    float l0 = logits[((size_t)(bm*4 + 0))*2048 + t];
    float l1 = logits[((size_t)(bm*4 + 1))*2048 + t];
    float l2 = logits[((size_t)(bm*4 + 2))*2048 + t];
    float l3 = logits[((size_t)(bm*4 + 3))*2048 + t];
    float m = fmaxf(fmaxf(l0, l1), fmaxf(l2, l3));
    float e0 = expf(l0 - m), e1 = expf(l1 - m), e2 = expf(l2 - m), e3 = expf(l3 - m);
    float inv = 1.0f / (e0 + e1 + e2 + e3);
    float o = 0.f;
    o += (e0*inv) * bf2f(oh16[((size_t)((bm*4+0)*2048 + t))*64 + lane]);
    o += (e1*inv) * bf2f(oh16[((size_t)((bm*4+1)*2048 + t))*64 + lane]);
    o += (e2*inv) * bf2f(oh16[((size_t)((bm*4+2)*2048 + t))*64 + lane]);
    o += (e3*inv) * bf2f(oh16[((size_t)((bm*4+3)*2048 + t))*64 + lane]);
    comb16[((size_t)(b*2048 + t))*512 + head*64 + lane] = f2bf(o);
}

// ---------------- K6: output GEMM + bias (bf16 MFMA, 64x64 block, 4 waves 2x2) ----------------
// A = comb16 [16384][512] bf16 row-major; B = WoutT16 [n][k] bf16.
// mfma_f32_16x16x32_bf16: A row=lane&15,k=(lane>>4)*8+e; B col=lane&15 same k;
// D col=lane&15, row=(lane>>4)*4+r  (per cdna_hip_programming §3, m89-verified).
__global__ __launch_bounds__(256) void k_gemm_out(
    const unsigned short* __restrict__ comb16, const unsigned short* __restrict__ WoutT16,
    const float* __restrict__ bias, float* __restrict__ out)
{
    __shared__ unsigned short Asl[64*72];   // [row][k], pitch 72 bf16 (144B)
    __shared__ unsigned short Bsl[64*72];   // [col][k], pitch 72
    const int bx = blockIdx.x;              // 256 m-tiles x 8 n-tiles
    const int mt = bx >> 3, nt = bx & 7;
    const int m0 = mt*64, n0 = nt*64;
    const int tid = threadIdx.x;
    const int wid = tid >> 6, lane = tid & 63;
    const int wm = wid >> 1, wn = wid & 1;
    const int l15 = lane & 15, l4 = lane >> 4;
    const int srow = tid >> 2, skb = (tid & 3) * 16;
    f32x4 acc[2][2] = {};
    for (int k0 = 0; k0 < 512; k0 += 64) {
        {
            const unsigned short* asrc = comb16 + (size_t)(m0 + srow)*512 + k0 + skb;
            *(uint4*)&Asl[srow*72 + skb]     = *(const uint4*)asrc;
            *(uint4*)&Asl[srow*72 + skb + 8] = *(const uint4*)(asrc + 8);
            const unsigned short* bsrc = WoutT16 + (size_t)(n0 + srow)*512 + k0 + skb;
            *(uint4*)&Bsl[srow*72 + skb]     = *(const uint4*)bsrc;
            *(uint4*)&Bsl[srow*72 + skb + 8] = *(const uint4*)(bsrc + 8);
        }
        __syncthreads();
        #pragma unroll
        for (int kq = 0; kq < 2; kq++) {
            int kb = kq*32 + l4*8;
            bf16x8 a0 = *(bf16x8*)&Asl[(wm*32 +      l15)*72 + kb];
            bf16x8 a1 = *(bf16x8*)&Asl[(wm*32 + 16 + l15)*72 + kb];
            bf16x8 b0 = *(bf16x8*)&Bsl[(wn*32 +      l15)*72 + kb];
            bf16x8 b1 = *(bf16x8*)&Bsl[(wn*32 + 16 + l15)*72 + kb];
            acc[0][0] = __builtin_amdgcn_mfma_f32_16x16x32_bf16(a0, b0, acc[0][0], 0, 0, 0);
            acc[0][1] = __builtin_amdgcn_mfma_f32_16x16x32_bf16(a0, b1, acc[0][1], 0, 0, 0);
            acc[1][0] = __builtin_amdgcn_mfma_f32_16x16x32_bf16(a1, b0, acc[1][0], 0, 0, 0);
            acc[1][1] = __builtin_amdgcn_mfma_f32_16x16x32_bf16(a1, b1, acc[1][1], 0, 0, 0);
        }
        __syncthreads();
    }
    #pragma unroll
    for (int sm = 0; sm < 2; sm++) {
        #pragma unroll
        for (int sn = 0; sn < 2; sn++) {
            int col = n0 + wn*32 + sn*16 + l15;
            float bb = bias[col];
            #pragma unroll
            for (int r = 0; r < 4; r++) {
                int row = m0 + wm*32 + sm*16 + l4*4 + r;
                out[(size_t)row*512 + col] = acc[sm][sn][r] + bb;
            }
        }
    }
}

extern "C" void kernel_launch(void* const* d_in, const int* in_sizes, int n_in,
                              void* d_out, int out_size, void* d_ws, size_t ws_size,
                              hipStream_t stream)
{
    const float* Q    = (const float*)d_in[0];
    const float* Wqk  = (const float*)d_in[3];
    const float* Wv   = (const float*)d_in[4];
    const float* Wout = (const float*)d_in[5];
    const float* bout = (const float*)d_in[6];
    const float* rot  = (const float*)d_in[7];
    float* ws = (float*)d_ws;
    float* qk     = ws;                       // 8,388,608 floats
    float* vv     = ws + 8388608;             // 8,388,608
    unsigned short* oh16 = (unsigned short*)(ws + 16777216);     // 33.5M ushort
    unsigned short* WoutT16 = (unsigned short*)(ws + 33554432);  // 262144 ushort (gap)
    unsigned short* comb16  = (unsigned short*)(ws + 50331648);  // 16.7M ushort
    float* rnorm  = ws + 58720256;            // 131,072
    float* logits = ws + 58851328;            // 524,288
    unsigned* buckets = (unsigned*)(ws + 59375616);   // 524,288
    unsigned* st      = (unsigned*)(ws + 59899904);   // 524,288
    float* rotT2  = ws + 60424192;            // 65,536
    float* out = (float*)d_out;

    k_rotT    <<<dim3(256),  dim3(256), 0, stream>>>(rot, rotT2);
    k_woutT   <<<dim3(1024), dim3(256), 0, stream>>>(Wout, WoutT16);
    k_gemm_qkv<<<dim3(1024), dim3(256), 0, stream>>>(Q, Wqk, Wv, qk, vv, rnorm);
    k_hash    <<<dim3(1024), dim3(256), 0, stream>>>(qk, rotT2, buckets);
    k_sort    <<<dim3(256),  dim3(256), 0, stream>>>(buckets, st);
    k_attn    <<<dim3(8192), dim3(256), 0, stream>>>(qk, vv, rnorm, st, oh16, logits);
    k_combine <<<dim3(32768),dim3(256), 0, stream>>>(oh16, logits, comb16);
    k_gemm_out<<<dim3(2048), dim3(256), 0, stream>>>(comb16, WoutT16, bout, out);
}

// Round 17
// 555.977 us; speedup vs baseline: 1.6344x; 1.1140x over previous
//
#include <hip/hip_runtime.h>
#include <math.h>

#define SELF_VAL (-5e4f)

typedef __attribute__((ext_vector_type(8))) short bf16x8;
typedef __attribute__((ext_vector_type(4))) float f32x4;

__device__ __forceinline__ unsigned short f2bf(float x) {
    unsigned b = __float_as_uint(x);
    b += 0x7FFFu + ((b >> 16) & 1u);
    return (unsigned short)(b >> 16);
}
__device__ __forceinline__ float bf2f(unsigned short h) {
    return __uint_as_float(((unsigned)h) << 16);
}

// ---------------- K0: re-layout rotations -> rotT2[h][k][col]  (4 x 64 x 256) ----------------
__global__ __launch_bounds__(256) void k_rotT(const float* __restrict__ rot,
                                              float* __restrict__ rotT2)
{
    int idx = blockIdx.x * 256 + threadIdx.x;    // 0..65535
    int h = idx >> 14, k = (idx >> 8) & 63, col = idx & 255;
    rotT2[idx] = rot[k * 1024 + h * 256 + col];
}

// ---------------- K0b: Wout -> transposed bf16 WoutT16[n][k] ----------------
__global__ __launch_bounds__(256) void k_woutT(const float* __restrict__ Wout,
                                               unsigned short* __restrict__ WoutT16)
{
    int idx = blockIdx.x * 256 + threadIdx.x;    // 0..262143
    int n = idx >> 9, k = idx & 511;
    WoutT16[idx] = f2bf(Wout[(size_t)k * 512 + n]);
}

// ---------------- K0c: Wv -> transposed bf16 WvT16[n][k] ----------------
__global__ __launch_bounds__(256) void k_wvT(const float* __restrict__ Wv,
                                             unsigned short* __restrict__ WvT16)
{
    int idx = blockIdx.x * 256 + threadIdx.x;    // 0..262143
    int n = idx >> 9, k = idx & 511;
    WvT16[idx] = f2bf(Wv[(size_t)k * 512 + n]);
}

// ---------------- K0d: Q -> bf16 row-major Q16 ----------------
__global__ __launch_bounds__(256) void k_q16(const float* __restrict__ Q,
                                             unsigned short* __restrict__ Q16)
{
    int idx = blockIdx.x * 256 + threadIdx.x;    // 0..1048575, 8 elems each
    const float* src = Q + (size_t)idx * 8;
    float4 v0 = *(const float4*)src;
    float4 v1 = *(const float4*)(src + 4);
    union { unsigned short s[8]; uint4 v; } ob;
    ob.s[0]=f2bf(v0.x); ob.s[1]=f2bf(v0.y); ob.s[2]=f2bf(v0.z); ob.s[3]=f2bf(v0.w);
    ob.s[4]=f2bf(v1.x); ob.s[5]=f2bf(v1.y); ob.s[6]=f2bf(v1.z); ob.s[7]=f2bf(v1.w);
    *(uint4*)(Q16 + (size_t)idx * 8) = ob.v;
}

// ---------------- K1: qk GEMM (f32, 128x128, 8x8/thread, T14 dbuf) + fused rnorm ----------------
// N=512 (Wqk only) — the hash path needs full f32 precision.
__global__ __launch_bounds__(256) void k_gemm_qk(
    const float* __restrict__ Q, const float* __restrict__ Wqk,
    float* __restrict__ qk, float* __restrict__ rnorm)
{
    __shared__ float As[16][132];   // transposed: As[k][m]
    __shared__ float Bs[16][132];
    const int bx = blockIdx.x;
    const int mt = bx >> 2, nt = bx & 3;
    const int m0 = mt * 128, n0 = nt * 128;
    const int tid = threadIdx.x;
    const int ty = tid >> 4, tx = tid & 15;
    const float* Bsrc = Wqk + n0;
    const int ar0 = tid >> 2, acq = (tid & 3) * 4;
    const int ar1 = 64 + (tid >> 2);
    const int bk0 = tid >> 5, bnq = (tid & 31) * 4;
    const int bk1 = 8 + (tid >> 5);
    const float* Aptr0 = Q + (size_t)(m0 + ar0) * 512 + acq;
    const float* Aptr1 = Q + (size_t)(m0 + ar1) * 512 + acq;
    const float* Bptr0 = Bsrc + (size_t)bk0 * 512 + bnq;
    const float* Bptr1 = Bsrc + (size_t)bk1 * 512 + bnq;
    float acc[8][8] = {};
    float4 a0 = *(const float4*)(Aptr0);
    float4 a1 = *(const float4*)(Aptr1);
    float4 b0 = *(const float4*)(Bptr0);
    float4 b1 = *(const float4*)(Bptr1);
    for (int k0 = 0; k0 < 512; k0 += 16) {
        As[acq+0][ar0]=a0.x; As[acq+1][ar0]=a0.y; As[acq+2][ar0]=a0.z; As[acq+3][ar0]=a0.w;
        As[acq+0][ar1]=a1.x; As[acq+1][ar1]=a1.y; As[acq+2][ar1]=a1.z; As[acq+3][ar1]=a1.w;
        *(float4*)&Bs[bk0][bnq] = b0;
        *(float4*)&Bs[bk1][bnq] = b1;
        __syncthreads();
        if (k0 + 16 < 512) {
            a0 = *(const float4*)(Aptr0 + k0 + 16);
            a1 = *(const float4*)(Aptr1 + k0 + 16);
            b0 = *(const float4*)(Bptr0 + (size_t)(k0 + 16) * 512);
            b1 = *(const float4*)(Bptr1 + (size_t)(k0 + 16) * 512);
        }
        #pragma unroll
        for (int kk = 0; kk < 16; kk++) {
            float a_[8], b_[8];
            *(float4*)&a_[0] = *(float4*)&As[kk][ty*4];
            *(float4*)&a_[4] = *(float4*)&As[kk][64 + ty*4];
            *(float4*)&b_[0] = *(float4*)&Bs[kk][tx*4];
            *(float4*)&b_[4] = *(float4*)&Bs[kk][64 + tx*4];
            #pragma unroll
            for (int i = 0; i < 8; i++)
                #pragma unroll
                for (int j = 0; j < 8; j++)
                    acc[i][j] += a_[i] * b_[j];
        }
        __syncthreads();
    }
    #pragma unroll
    for (int ig = 0; ig < 2; ig++) {
        #pragma unroll
        for (int i = 0; i < 4; i++) {
            int row = m0 + ig*64 + ty*4 + i;
            int b = row >> 11, t = row & 2047;
            #pragma unroll
            for (int jg = 0; jg < 2; jg++) {
                int n = n0 + jg*64 + tx*4;
                float4 r4 = make_float4(acc[ig*4+i][jg*4+0], acc[ig*4+i][jg*4+1],
                                        acc[ig*4+i][jg*4+2], acc[ig*4+i][jg*4+3]);
                *(float4*)(qk + ((size_t)((b*8 + (n>>6))*2048 + t))*64 + (n&63)) = r4;
            }
        }
    }
    // ---- fused rnorm: 2 heads x 128 tokens per block ----
    #pragma unroll
    for (int jg = 0; jg < 2; jg++) {
        int h = (n0 + jg*64) >> 6;
        #pragma unroll
        for (int ig = 0; ig < 2; ig++) {
            #pragma unroll
            for (int i = 0; i < 4; i++) {
                float s = acc[ig*4+i][jg*4+0]*acc[ig*4+i][jg*4+0]
                        + acc[ig*4+i][jg*4+1]*acc[ig*4+i][jg*4+1]
                        + acc[ig*4+i][jg*4+2]*acc[ig*4+i][jg*4+2]
                        + acc[ig*4+i][jg*4+3]*acc[ig*4+i][jg*4+3];
                s += __shfl_xor(s, 1);
                s += __shfl_xor(s, 2);
                s += __shfl_xor(s, 4);
                s += __shfl_xor(s, 8);
                if (tx == 0) {
                    int row = m0 + ig*64 + ty*4 + i;
                    int b = row >> 11, t = row & 2047;
                    rnorm[((size_t)(b*8 + h))*2048 + t] = 1.0f / fmaxf(sqrtf(s), 1e-12f);
                }
            }
        }
    }
}

// ---------------- K1b: v GEMM (bf16 MFMA, 64x64 block, 4 waves 2x2) ----------------
// A = Q16 [16384][512]; B = WvT16 [n][k]; writes vv f32 head-major.
__global__ __launch_bounds__(256) void k_gemm_v(
    const unsigned short* __restrict__ Q16, const unsigned short* __restrict__ WvT16,
    float* __restrict__ vv)
{
    __shared__ unsigned short Asl[64*72];
    __shared__ unsigned short Bsl[64*72];
    const int bx = blockIdx.x;              // 256 m-tiles x 8 n-tiles
    const int mt = bx >> 3, nt = bx & 7;
    const int m0 = mt*64, n0 = nt*64;
    const int tid = threadIdx.x;
    const int wid = tid >> 6, lane = tid & 63;
    const int wm = wid >> 1, wn = wid & 1;
    const int l15 = lane & 15, l4 = lane >> 4;
    const int srow = tid >> 2, skb = (tid & 3) * 16;
    f32x4 acc[2][2] = {};
    for (int k0 = 0; k0 < 512; k0 += 64) {
        {
            const unsigned short* asrc = Q16 + (size_t)(m0 + srow)*512 + k0 + skb;
            *(uint4*)&Asl[srow*72 + skb]     = *(const uint4*)asrc;
            *(uint4*)&Asl[srow*72 + skb + 8] = *(const uint4*)(asrc + 8);
            const unsigned short* bsrc = WvT16 + (size_t)(n0 + srow)*512 + k0 + skb;
            *(uint4*)&Bsl[srow*72 + skb]     = *(const uint4*)bsrc;
            *(uint4*)&Bsl[srow*72 + skb + 8] = *(const uint4*)(bsrc + 8);
        }
        __syncthreads();
        #pragma unroll
        for (int kq = 0; kq < 2; kq++) {
            int kb = kq*32 + l4*8;
            bf16x8 a0 = *(bf16x8*)&Asl[(wm*32 +      l15)*72 + kb];
            bf16x8 a1 = *(bf16x8*)&Asl[(wm*32 + 16 + l15)*72 + kb];
            bf16x8 b0 = *(bf16x8*)&Bsl[(wn*32 +      l15)*72 + kb];
            bf16x8 b1 = *(bf16x8*)&Bsl[(wn*32 + 16 + l15)*72 + kb];
            acc[0][0] = __builtin_amdgcn_mfma_f32_16x16x32_bf16(a0, b0, acc[0][0], 0, 0, 0);
            acc[0][1] = __builtin_amdgcn_mfma_f32_16x16x32_bf16(a0, b1, acc[0][1], 0, 0, 0);
            acc[1][0] = __builtin_amdgcn_mfma_f32_16x16x32_bf16(a1, b0, acc[1][0], 0, 0, 0);
            acc[1][1] = __builtin_amdgcn_mfma_f32_16x16x32_bf16(a1, b1, acc[1][1], 0, 0, 0);
        }
        __syncthreads();
    }
    #pragma unroll
    for (int sm = 0; sm < 2; sm++) {
        #pragma unroll
        for (int sn = 0; sn < 2; sn++) {
            int col = n0 + wn*32 + sn*16 + l15;
            int h = col >> 6, d = col & 63;
            #pragma unroll
            for (int r = 0; r < 4; r++) {
                int row = m0 + wm*32 + sm*16 + l4*4 + r;
                int b = row >> 11, t = row & 2047;
                vv[((size_t)((b*8 + h)*2048 + t))*64 + d] = acc[sm][sn][r];
            }
        }
    }
}

// ---------------- K2: hash = f32 GEMM (128 tokens, K=64) + signed argmax ----------------
// FROZEN round-6 body (287 us, VGPR 64, VALUBusy 70%).
__global__ __launch_bounds__(256) void k_hash(const float* __restrict__ qk,
    const float* __restrict__ rotT2, unsigned* __restrict__ buckets)
{
    __shared__ float As[64*128];    // As[k][row], pitch 128 (32 KB)
    const int bx = blockIdx.x;
    const int bm = bx >> 4;
    const int row0 = (bx & 15) << 7;             // token base within bm
    const int tid = threadIdx.x;
    const int ty = tid >> 4, tx = tid & 15;
    {
        const int r = tid >> 1;
        const int kb = (tid & 1) * 8;            // float4 units
        const float* src = qk + ((size_t)(bm*2048 + row0 + r))*64;
        #pragma unroll
        for (int c = 0; c < 8; c++) {
            float4 a4 = *(const float4*)(src + (size_t)(kb + c)*4);
            int k = (kb + c)*4;
            As[(k+0)*128 + r] = a4.x;
            As[(k+1)*128 + r] = a4.y;
            As[(k+2)*128 + r] = a4.z;
            As[(k+3)*128 + r] = a4.w;
        }
    }
    __syncthreads();
    #pragma unroll 1
    for (int h = 0; h < 4; h++) {
        float bv[8]; unsigned bi[8];
        #pragma unroll
        for (int i = 0; i < 8; i++) { bv[i] = -3.402823466e38f; bi[i] = 0u; }
        #pragma unroll 1
        for (int ch = 0; ch < 4; ch++) {
            const float* bsrc = rotT2 + (size_t)h*16384 + ch*64 + tx*4;
            float acc[8][4] = {};
            #pragma unroll 16
            for (int kk = 0; kk < 64; kk++) {
                float4 b4 = *(const float4*)(bsrc + (size_t)kk*256);
                float a_[8];
                *(float4*)&a_[0] = *(float4*)&As[kk*128 + ty*4];
                *(float4*)&a_[4] = *(float4*)&As[kk*128 + 64 + ty*4];
                float b_[4] = {b4.x, b4.y, b4.z, b4.w};
                #pragma unroll
                for (int i = 0; i < 8; i++)
                    #pragma unroll
                    for (int j = 0; j < 4; j++)
                        acc[i][j] += a_[i] * b_[j];
            }
            #pragma unroll
            for (int j = 0; j < 4; j++) {
                unsigned c0 = (unsigned)(ch*64 + tx*4 + j);
                unsigned nc0 = 256u + c0;
                #pragma unroll
                for (int i = 0; i < 8; i++) {
                    float v = acc[i][j];
                    if (v > bv[i] || (v == bv[i] && c0 < bi[i])) { bv[i] = v; bi[i] = c0; }
                    float nv = -v;
                    if (nv > bv[i] || (nv == bv[i] && nc0 < bi[i])) { bv[i] = nv; bi[i] = nc0; }
                }
            }
        }
        #pragma unroll
        for (int i = 0; i < 8; i++) {
            #pragma unroll
            for (int d = 1; d < 16; d <<= 1) {
                float ov = __shfl_xor(bv[i], d);
                unsigned oi = (unsigned)__shfl_xor((int)bi[i], d);
                if (ov > bv[i] || (ov == bv[i] && oi < bi[i])) { bv[i] = ov; bi[i] = oi; }
            }
        }
        if (tx == 0) {
            #pragma unroll
            for (int i = 0; i < 8; i++) {
                int r = (i < 4) ? (ty*4 + i) : (64 + ty*4 + (i - 4));
                buckets[((size_t)(bm*4 + h))*2048 + row0 + r] = bi[i];
            }
        }
    }
}

// ---------------- K3: stable counting sort per (bm,hash) ----------------
__global__ __launch_bounds__(256) void k_sort(const unsigned* __restrict__ buckets,
                                              unsigned* __restrict__ st)
{
    __shared__ unsigned whist[4][512];
    __shared__ unsigned baseb[512];
    const int seg = blockIdx.x;                  // bm*4+h
    const unsigned* bk = buckets + (size_t)seg * 2048;
    unsigned* out = st + (size_t)seg * 2048;
    const int tid = threadIdx.x, w = tid >> 6, lane = tid & 63;
    for (int b = tid; b < 2048; b += 256) ((unsigned*)whist)[b] = 0u;
    __syncthreads();
    unsigned myb[8];
    #pragma unroll
    for (int r = 0; r < 8; r++) {
        int pos = w*512 + r*64 + lane;
        myb[r] = bk[pos];
        atomicAdd(&whist[w][myb[r]], 1u);
    }
    __syncthreads();
    for (int b = tid; b < 512; b += 256) {
        unsigned p = 0;
        #pragma unroll
        for (int ww = 0; ww < 4; ww++) { unsigned t = whist[ww][b]; whist[ww][b] = p; p += t; }
        baseb[b] = p;
    }
    __syncthreads();
    if (tid == 0) {
        unsigned run = 0;
        for (int b = 0; b < 512; b++) { unsigned t = baseb[b]; baseb[b] = run; run += t; }
    }
    __syncthreads();
    for (int b = tid; b < 512; b += 256) {
        unsigned bb = baseb[b];
        #pragma unroll
        for (int ww = 0; ww < 4; ww++) whist[ww][b] += bb;
    }
    __syncthreads();
    for (int r = 0; r < 8; r++) {
        unsigned b = myb[r];
        int pos = w*512 + r*64 + lane;
        unsigned base = whist[w][b];             // read before this round's bumps
        unsigned rank = 0;
        for (int j = 0; j < 64; j++) {
            unsigned bj = __shfl(b, j);
            rank += (j < lane && bj == b) ? 1u : 0u;
        }
        out[base + rank] = (unsigned)pos;
        atomicAdd(&whist[w][b], 1u);
    }
}

// ---------------- K4: chunked LSH attention (bf16 oh output) ----------------
__global__ __launch_bounds__(256) void k_attn(const float* __restrict__ qk,
    const float* __restrict__ vv, const float* __restrict__ rnorm,
    const unsigned* __restrict__ st, unsigned short* __restrict__ oh16,
    float* __restrict__ logits)
{
    __shared__ float qs[68][68];
    __shared__ float vs[68][68];
    __shared__ unsigned P[68];
    __shared__ float rn[68];
    const int sid = blockIdx.x;
    const int stripi = sid & 31;
    const int seg = sid >> 5;
    const int bm = seg >> 2, h = seg & 3;
    const int G0 = (h*512 + stripi*16) * 4;      // first q slot (global, 0..8191)
    const int tid = threadIdx.x;
    for (int j = tid; j < 68; j += 256) {
        int G = (G0 - 4 + j) & 8191;
        int hg = G >> 11, sg = G & 2047;
        unsigned tok = st[((size_t)(bm*4 + hg))*2048 + sg];
        P[j] = tok;
        rn[j] = rnorm[bm*2048 + (int)tok];
    }
    __syncthreads();
    for (int e = tid; e < 68*16; e += 256) {
        int j = e >> 4, fq = e & 15;
        unsigned tok = P[j];
        size_t base = ((size_t)(bm*2048 + (int)tok))*64 + fq*4;
        *(float4*)&qs[j][fq*4] = *(const float4*)(qk + base);
        *(float4*)&vs[j][fq*4] = *(const float4*)(vv + base);
    }
    __syncthreads();
    const int w = tid >> 6, lane = tid & 63;
    const int half = lane >> 5, qi = (lane >> 3) & 3, jj = lane & 7;
    const int fb = lane & 7;
    for (int cp = 0; cp < 2; cp++) {
        int c = w*4 + cp*2 + half;               // local chunk 0..15
        int jq = 4 + c*4 + qi;
        int jk = c*4 + jj;
        float dot = 0.f;
        #pragma unroll
        for (int fq = 0; fq < 16; fq++) {
            float4 q4 = *(float4*)&qs[jq][fq*4];
            float4 k4 = *(float4*)&qs[jk][fq*4];
            dot += q4.x*k4.x + q4.y*k4.y + q4.z*k4.z + q4.w*k4.w;
        }
        dot *= 0.125f * rn[jk];
        if (P[jq] == P[jk]) dot = SELF_VAL;
        float m = dot;
        m = fmaxf(m, __shfl_xor(m, 1));
        m = fmaxf(m, __shfl_xor(m, 2));
        m = fmaxf(m, __shfl_xor(m, 4));
        float ex = expf(dot - m);
        float s = ex;
        s += __shfl_xor(s, 1); s += __shfl_xor(s, 2); s += __shfl_xor(s, 4);
        float lse = m + logf(s);
        float p = expf(dot - lse);
        unsigned tq = P[jq];
        if (jj == 0) logits[((size_t)(bm*4 + h))*2048 + tq] = lse;
        float a0=0,a1=0,a2=0,a3=0,a4a=0,a5=0,a6=0,a7=0;
        #pragma unroll
        for (int j2 = 0; j2 < 8; j2++) {
            float pj = __shfl(p, (lane & 0x38) | j2);
            float4 va = *(float4*)&vs[c*4 + j2][fb*8];
            float4 vb = *(float4*)&vs[c*4 + j2][fb*8 + 4];
            a0 += pj*va.x; a1 += pj*va.y; a2 += pj*va.z; a3 += pj*va.w;
            a4a += pj*vb.x; a5 += pj*vb.y; a6 += pj*vb.z; a7 += pj*vb.w;
        }
        union { unsigned short s[8]; uint4 v; } ob;
        ob.s[0]=f2bf(a0); ob.s[1]=f2bf(a1); ob.s[2]=f2bf(a2); ob.s[3]=f2bf(a3);
        ob.s[4]=f2bf(a4a); ob.s[5]=f2bf(a5); ob.s[6]=f2bf(a6); ob.s[7]=f2bf(a7);
        *(uint4*)(oh16 + ((size_t)((bm*4 + h)*2048 + (int)tq))*64 + fb*8) = ob.v;
    }
}

// ---------------- K5: combine hash rounds (bf16 in, bf16 out) ----------------
__global__ __launch_bounds__(256) void k_combine(const unsigned short* __restrict__ oh16,
    const float* __restrict__ logits, unsigned short* __restrict__ comb16)
{
    int w = threadIdx.x >> 6, lane = threadIdx.x & 63;
    int row = blockIdx.x * 4 + w;                // bm*2048+t
    int bm = row >> 11, t = row & 2047;
    int b = bm >> 3, head = bm & 7;
    float l0 = logits[((size_t)(bm*4 + 0))*2048 + t];
    float l1 = logits[((size_t)(bm*4 + 1))*2048 + t];
    float l2 = logits[((size_t)(bm*4 + 2))*2048 + t];
    float l3 = logits[((size_t)(bm*4 + 3))*2048 + t];
    float m = fmaxf(fmaxf(l0, l1), fmaxf(l2, l3));
    float e0 = expf(l0 - m), e1 = expf(l1 - m), e2 = expf(l2 - m), e3 = expf(l3 - m);
    float inv = 1.0f / (e0 + e1 + e2 + e3);
    float o = 0.f;
    o += (e0*inv) * bf2f(oh16[((size_t)((bm*4+0)*2048 + t))*64 + lane]);
    o += (e1*inv) * bf2f(oh16[((size_t)((bm*4+1)*2048 + t))*64 + lane]);
    o += (e2*inv) * bf2f(oh16[((size_t)((bm*4+2)*2048 + t))*64 + lane]);
    o += (e3*inv) * bf2f(oh16[((size_t)((bm*4+3)*2048 + t))*64 + lane]);
    comb16[((size_t)(b*2048 + t))*512 + head*64 + lane] = f2bf(o);
}

// ---------------- K6: output GEMM + bias (bf16 MFMA, 64x64 block, 4 waves 2x2) ----------------
__global__ __launch_bounds__(256) void k_gemm_out(
    const unsigned short* __restrict__ comb16, const unsigned short* __restrict__ WoutT16,
    const float* __restrict__ bias, float* __restrict__ out)
{
    __shared__ unsigned short Asl[64*72];
    __shared__ unsigned short Bsl[64*72];
    const int bx = blockIdx.x;              // 256 m-tiles x 8 n-tiles
    const int mt = bx >> 3, nt = bx & 7;
    const int m0 = mt*64, n0 = nt*64;
    const int tid = threadIdx.x;
    const int wid = tid >> 6, lane = tid & 63;
    const int wm = wid >> 1, wn = wid & 1;
    const int l15 = lane & 15, l4 = lane >> 4;
    const int srow = tid >> 2, skb = (tid & 3) * 16;
    f32x4 acc[2][2] = {};
    for (int k0 = 0; k0 < 512; k0 += 64) {
        {
            const unsigned short* asrc = comb16 + (size_t)(m0 + srow)*512 + k0 + skb;
            *(uint4*)&Asl[srow*72 + skb]     = *(const uint4*)asrc;
            *(uint4*)&Asl[srow*72 + skb + 8] = *(const uint4*)(asrc + 8);
            const unsigned short* bsrc = WoutT16 + (size_t)(n0 + srow)*512 + k0 + skb;
            *(uint4*)&Bsl[srow*72 + skb]     = *(const uint4*)bsrc;
            *(uint4*)&Bsl[srow*72 + skb + 8] = *(const uint4*)(bsrc + 8);
        }
        __syncthreads();
        #pragma unroll
        for (int kq = 0; kq < 2; kq++) {
            int kb = kq*32 + l4*8;
            bf16x8 a0 = *(bf16x8*)&Asl[(wm*32 +      l15)*72 + kb];
            bf16x8 a1 = *(bf16x8*)&Asl[(wm*32 + 16 + l15)*72 + kb];
            bf16x8 b0 = *(bf16x8*)&Bsl[(wn*32 +      l15)*72 + kb];
            bf16x8 b1 = *(bf16x8*)&Bsl[(wn*32 + 16 + l15)*72 + kb];
            acc[0][0] = __builtin_amdgcn_mfma_f32_16x16x32_bf16(a0, b0, acc[0][0], 0, 0, 0);
            acc[0][1] = __builtin_amdgcn_mfma_f32_16x16x32_bf16(a0, b1, acc[0][1], 0, 0, 0);
            acc[1][0] = __builtin_amdgcn_mfma_f32_16x16x32_bf16(a1, b0, acc[1][0], 0, 0, 0);
            acc[1][1] = __builtin_amdgcn_mfma_f32_16x16x32_bf16(a1, b1, acc[1][1], 0, 0, 0);
        }
        __syncthreads();
    }
    #pragma unroll
    for (int sm = 0; sm < 2; sm++) {
        #pragma unroll
        for (int sn = 0; sn < 2; sn++) {
            int col = n0 + wn*32 + sn*16 + l15;
            float bb = bias[col];
            #pragma unroll
            for (int r = 0; r < 4; r++) {
                int row = m0 + wm*32 + sm*16 + l4*4 + r;
                out[(size_t)row*512 + col] = acc[sm][sn][r] + bb;
            }
        }
    }
}

extern "C" void kernel_launch(void* const* d_in, const int* in_sizes, int n_in,
                              void* d_out, int out_size, void* d_ws, size_t ws_size,
                              hipStream_t stream)
{
    const float* Q    = (const float*)d_in[0];
    const float* Wqk  = (const float*)d_in[3];
    const float* Wv   = (const float*)d_in[4];
    const float* Wout = (const float*)d_in[5];
    const float* bout = (const float*)d_in[6];
    const float* rot  = (const float*)d_in[7];
    float* ws = (float*)d_ws;
    float* qk     = ws;                       // 8,388,608 floats
    float* vv     = ws + 8388608;             // 8,388,608
    unsigned short* oh16 = (unsigned short*)(ws + 16777216);     // 33.5M ushort
    unsigned short* WoutT16 = (unsigned short*)(ws + 33554432);  // 262144 ushort
    unsigned short* Q16     = (unsigned short*)(ws + 33685504);  // 8.4M ushort
    unsigned short* WvT16   = (unsigned short*)(ws + 37879808);  // 262144 ushort
    unsigned short* comb16  = (unsigned short*)(ws + 50331648);  // 16.7M ushort
    float* rnorm  = ws + 58720256;            // 131,072
    float* logits = ws + 58851328;            // 524,288
    unsigned* buckets = (unsigned*)(ws + 59375616);   // 524,288
    unsigned* st      = (unsigned*)(ws + 59899904);   // 524,288
    float* rotT2  = ws + 60424192;            // 65,536
    float* out = (float*)d_out;

    k_rotT    <<<dim3(256),  dim3(256), 0, stream>>>(rot, rotT2);
    k_woutT   <<<dim3(1024), dim3(256), 0, stream>>>(Wout, WoutT16);
    k_wvT     <<<dim3(1024), dim3(256), 0, stream>>>(Wv, WvT16);
    k_q16     <<<dim3(4096), dim3(256), 0, stream>>>(Q, Q16);
    k_gemm_qk <<<dim3(512),  dim3(256), 0, stream>>>(Q, Wqk, qk, rnorm);
    k_gemm_v  <<<dim3(2048), dim3(256), 0, stream>>>(Q16, WvT16, vv);
    k_hash    <<<dim3(1024), dim3(256), 0, stream>>>(qk, rotT2, buckets);
    k_sort    <<<dim3(256),  dim3(256), 0, stream>>>(buckets, st);
    k_attn    <<<dim3(8192), dim3(256), 0, stream>>>(qk, vv, rnorm, st, oh16, logits);
    k_combine <<<dim3(32768),dim3(256), 0, stream>>>(oh16, logits, comb16);
    k_gemm_out<<<dim3(2048), dim3(256), 0, stream>>>(comb16, WoutT16, bout, out);
}